// Round 3
// baseline (308.291 us; speedup 1.0000x reference)
//
#include <hip/hip_runtime.h>

// ---------------------------------------------------------------------------
// Swin-style windowed MHA block, MI355X/gfx950.
// WS=8, N=64 tokens/window, C=192, NH=6 heads, HD=32, B=8, H=W=128,
// 2048 windows total.
//
// Pipeline:
//   prep_kernel : weights fp32->bf16 (Q rows pre-scaled by 1/sqrt(32)),
//                 bias table gathered into per-lane MFMA C-fragment layout.
//   attn_kernel : 1 block/window, 6 waves (1/head). Fused QKV -> scores^T
//                 (mfma(K,Q^T)) + bias -> softmax -> PV -> proj -> +x.
//                 Writes y = x + attn to windowed bf16 scratch (coalesced).
//   mlp_kernel  : 1 block/window, 4 waves. GEMM1 -> GLU -> GEMM2 -> out=y+m.
// ---------------------------------------------------------------------------

typedef short          s16x8 __attribute__((ext_vector_type(8)));
typedef unsigned short u16x4 __attribute__((ext_vector_type(4)));
typedef unsigned short u16x8 __attribute__((ext_vector_type(8)));
typedef float          f32x4 __attribute__((ext_vector_type(4)));

#define MFMA(A, B, C) __builtin_amdgcn_mfma_f32_16x16x32_bf16((A), (B), (C), 0, 0, 0)

__device__ __forceinline__ unsigned short f2b(float f) {
  unsigned x = __float_as_uint(f);
  x = (x + 0x7FFFu + ((x >> 16) & 1u)) >> 16;   // RNE
  return (unsigned short)x;
}
__device__ __forceinline__ float b2f(unsigned short u) {
  return __uint_as_float(((unsigned)u) << 16);
}

#define XSTR   200      // padded row stride (elems) for [64][192] LDS tiles
#define S_QK   40       // padded row stride for Q/K [64][32]
#define S_P    72       // padded row stride for P  [64][64]
#define S_VT   72       // padded row stride for Vt [32][64]
#define HREG   7424     // per-head LDS elems: Q(2560)+K(2560)+Vt(2304); P reuses Q+K
#define QSCALE 0.17677669529663687f

// workspace element offsets (ushort units unless noted)
#define WOFF_QKV   0
#define WOFF_PROJ  110592
#define WOFF_MLP1  147456
#define WOFF_MLP2  221184
#define WOFF_BIASX_BYTES 516096           // float[4096]
#define WOFF_YWIN_BYTES  532480           // ushort[2048*64*192]

// ---------------------------------------------------------------------------
__global__ void prep_kernel(const float* __restrict__ qkv_w,
                            const float* __restrict__ proj_w,
                            const float* __restrict__ mlp1_w,
                            const float* __restrict__ mlp2_w,
                            const float* __restrict__ bias_table,
                            const int*   __restrict__ rel_index,
                            unsigned short* __restrict__ qkv_wb,
                            unsigned short* __restrict__ proj_wb,
                            unsigned short* __restrict__ mlp1_wb,
                            unsigned short* __restrict__ mlp2_wb,
                            float* __restrict__ biasx) {
  int j = blockIdx.x * 256 + threadIdx.x;   // 1024*256 = 262144 jobs exactly
  if (j < 110592) {
    float v = qkv_w[j];
    if (j < 36864) v *= QSCALE;             // fold 1/sqrt(HD) into Q rows
    qkv_wb[j] = f2b(v);
  } else if (j < 147456) {
    proj_wb[j - 110592] = f2b(proj_w[j - 110592]);
  } else if (j < 221184) {
    mlp1_wb[j - 147456] = f2b(mlp1_w[j - 147456]);
  } else if (j < 258048) {
    mlp2_wb[j - 221184] = f2b(mlp2_w[j - 221184]);
  } else {
    int e = j - 258048;                     // 0..4095
    int l = e >> 6, v = e & 63;
    int tm = v >> 4, tn = (v >> 2) & 3, r = v & 3;
    int q = tn * 16 + (l & 15);
    int k = tm * 16 + (l >> 4) * 4 + r;
    biasx[e] = bias_table[rel_index[q * 64 + k]];
  }
}

// ---------------------------------------------------------------------------
__global__ __launch_bounds__(384) void attn_kernel(
    const float* __restrict__ x,
    const unsigned short* __restrict__ qkv_wb, const float* __restrict__ qkv_b,
    const unsigned short* __restrict__ proj_wb, const float* __restrict__ proj_b,
    const float* __restrict__ biasx,
    unsigned short* __restrict__ y_win) {
  __shared__ __align__(16) unsigned short sm[64 * XSTR + 6 * HREG];  // 114688 B

  const int tid  = threadIdx.x;
  const int lane = tid & 63;
  const int wv   = tid >> 6;      // head index, 0..5
  const int l15  = lane & 15;
  const int lg   = lane >> 4;     // 0..3
  const int win  = blockIdx.x;
  const int bb   = win >> 8;
  const int wh   = (win >> 4) & 15;
  const int wwi  = win & 15;

  unsigned short* xa = sm;        // [64 tokens][XSTR] bf16 of x-window
  const float* xwin = x + (size_t)bb * 192 * 16384 + (size_t)(wh * 8) * 128 + wwi * 8;

  // ---- stage x window -> LDS bf16 (jobs: 192 ch * 8 rows, 32B reads) ----
#pragma unroll
  for (int it = 0; it < 4; ++it) {
    int job = tid + 384 * it;     // 1536 jobs
    int c = job >> 3, i = job & 7;
    const float* src = xwin + (size_t)c * 16384 + i * 128;
    f32x4 v0 = *(const f32x4*)(src);
    f32x4 v1 = *(const f32x4*)(src + 4);
    unsigned short* dst = &xa[(i * 8) * XSTR + c];
    dst[0 * XSTR] = f2b(v0[0]); dst[1 * XSTR] = f2b(v0[1]);
    dst[2 * XSTR] = f2b(v0[2]); dst[3 * XSTR] = f2b(v0[3]);
    dst[4 * XSTR] = f2b(v1[0]); dst[5 * XSTR] = f2b(v1[1]);
    dst[6 * XSTR] = f2b(v1[2]); dst[7 * XSTR] = f2b(v1[3]);
  }
  __syncthreads();  // B0: xa visible to all waves

  unsigned short* hreg = sm + 64 * XSTR + wv * HREG;
  unsigned short* Qs  = hreg;             // [64][S_QK]
  unsigned short* Ks  = hreg + 2560;      // [64][S_QK]
  unsigned short* Ps  = hreg;             // [64][S_P], reuses Q+K after scores
  unsigned short* Vts = hreg + 5120;      // [32][S_VT], V transposed

  // ---------------- QKV GEMM: [64x192] x [192x32] per head, x3 ----------------
  f32x4 accq[4][2], acck[4][2], accv[4][2];
#pragma unroll
  for (int nt = 0; nt < 2; ++nt) {
    const int o = wv * 32 + nt * 16 + l15;
    const float bq = qkv_b[o] * QSCALE;
    const float bk = qkv_b[192 + o];
    const float bv = qkv_b[384 + o];
#pragma unroll
    for (int m = 0; m < 4; ++m) {
      accq[m][nt] = (f32x4){bq, bq, bq, bq};
      acck[m][nt] = (f32x4){bk, bk, bk, bk};
      accv[m][nt] = (f32x4){bv, bv, bv, bv};
    }
  }
#pragma unroll
  for (int ks = 0; ks < 6; ++ks) {
    const int k0 = ks * 32 + lg * 8;
    s16x8 af[4];
#pragma unroll
    for (int m = 0; m < 4; ++m)
      af[m] = *(const s16x8*)&xa[(m * 16 + l15) * XSTR + k0];
#pragma unroll
    for (int nt = 0; nt < 2; ++nt) {
      const int o = wv * 32 + nt * 16 + l15;
      s16x8 wq  = *(const s16x8*)&qkv_wb[(size_t)o * 192 + k0];
      s16x8 wk  = *(const s16x8*)&qkv_wb[(size_t)(192 + o) * 192 + k0];
      s16x8 wvv = *(const s16x8*)&qkv_wb[(size_t)(384 + o) * 192 + k0];
#pragma unroll
      for (int m = 0; m < 4; ++m) {
        accq[m][nt] = MFMA(af[m], wq , accq[m][nt]);
        acck[m][nt] = MFMA(af[m], wk , acck[m][nt]);
        accv[m][nt] = MFMA(af[m], wvv, accv[m][nt]);
      }
    }
  }
  // write Q,K row-major; V transposed (packed b64)
#pragma unroll
  for (int m = 0; m < 4; ++m) {
#pragma unroll
    for (int nt = 0; nt < 2; ++nt) {
      const int d = nt * 16 + l15;
#pragma unroll
      for (int r = 0; r < 4; ++r) {
        const int t = m * 16 + lg * 4 + r;
        Qs[t * S_QK + d] = f2b(accq[m][nt][r]);
        Ks[t * S_QK + d] = f2b(acck[m][nt][r]);
      }
      u16x4 pv;
      pv[0] = f2b(accv[m][nt][0]); pv[1] = f2b(accv[m][nt][1]);
      pv[2] = f2b(accv[m][nt][2]); pv[3] = f2b(accv[m][nt][3]);
      *(u16x4*)&Vts[d * S_VT + m * 16 + lg * 4] = pv;
    }
  }
  __syncthreads();  // B1

  // ---------------- scores^T = K . Q^T + bias ----------------
  const float* bxp = biasx + lane * 64;
  s16x8 kf[4], qf[4];
#pragma unroll
  for (int tm = 0; tm < 4; ++tm)
    kf[tm] = *(const s16x8*)&Ks[(tm * 16 + l15) * S_QK + lg * 8];
#pragma unroll
  for (int tn = 0; tn < 4; ++tn)
    qf[tn] = *(const s16x8*)&Qs[(tn * 16 + l15) * S_QK + lg * 8];
  f32x4 sc[4][4];
#pragma unroll
  for (int tm = 0; tm < 4; ++tm)
#pragma unroll
    for (int tn = 0; tn < 4; ++tn) {
      f32x4 bfr = *(const f32x4*)&bxp[tm * 16 + tn * 4];
      sc[tm][tn] = MFMA(kf[tm], qf[tn], bfr);
    }
  // softmax over keys (rows of scores^T): 16 in-lane + shfl_xor 16,32
#pragma unroll
  for (int tn = 0; tn < 4; ++tn) {
    float mx = sc[0][tn][0];
#pragma unroll
    for (int tm = 0; tm < 4; ++tm)
#pragma unroll
      for (int r = 0; r < 4; ++r) mx = fmaxf(mx, sc[tm][tn][r]);
    mx = fmaxf(mx, __shfl_xor(mx, 16));
    mx = fmaxf(mx, __shfl_xor(mx, 32));
    float sum = 0.f;
#pragma unroll
    for (int tm = 0; tm < 4; ++tm)
#pragma unroll
      for (int r = 0; r < 4; ++r) {
        float e = __expf(sc[tm][tn][r] - mx);
        sc[tm][tn][r] = e;
        sum += e;
      }
    sum += __shfl_xor(sum, 16);
    sum += __shfl_xor(sum, 32);
    const float inv = 1.0f / sum;
#pragma unroll
    for (int tm = 0; tm < 4; ++tm)
#pragma unroll
      for (int r = 0; r < 4; ++r) sc[tm][tn][r] *= inv;
  }
  __syncthreads();  // B2: all K/Q fragment reads done; P may overwrite
#pragma unroll
  for (int tm = 0; tm < 4; ++tm)
#pragma unroll
    for (int tn = 0; tn < 4; ++tn) {
      u16x4 pv;
      pv[0] = f2b(sc[tm][tn][0]); pv[1] = f2b(sc[tm][tn][1]);
      pv[2] = f2b(sc[tm][tn][2]); pv[3] = f2b(sc[tm][tn][3]);
      *(u16x4*)&Ps[(tn * 16 + l15) * S_P + tm * 16 + lg * 4] = pv;
    }
  __syncthreads();  // B3: P visible

  // ---------------- PV: out[q][d] = P[64x64] . V[64x32] ----------------
  f32x4 oacc[4][2];
#pragma unroll
  for (int m = 0; m < 4; ++m)
#pragma unroll
    for (int nt = 0; nt < 2; ++nt) oacc[m][nt] = (f32x4){0.f, 0.f, 0.f, 0.f};
#pragma unroll
  for (int ks = 0; ks < 2; ++ks) {
    s16x8 ap[4], bv2[2];
#pragma unroll
    for (int m = 0; m < 4; ++m)
      ap[m] = *(const s16x8*)&Ps[(m * 16 + l15) * S_P + ks * 32 + lg * 8];
#pragma unroll
    for (int nt = 0; nt < 2; ++nt)
      bv2[nt] = *(const s16x8*)&Vts[(nt * 16 + l15) * S_VT + ks * 32 + lg * 8];
#pragma unroll
    for (int m = 0; m < 4; ++m)
#pragma unroll
      for (int nt = 0; nt < 2; ++nt)
        oacc[m][nt] = MFMA(ap[m], bv2[nt], oacc[m][nt]);
  }
  __syncthreads();  // B4: P reads done; attn-out may overwrite head region
#pragma unroll
  for (int m = 0; m < 4; ++m)
#pragma unroll
    for (int nt = 0; nt < 2; ++nt) {
      const int d = nt * 16 + l15;
#pragma unroll
      for (int r = 0; r < 4; ++r)
        hreg[(m * 16 + lg * 4 + r) * 32 + d] = f2b(oacc[m][nt][r]);
    }
  __syncthreads();  // B5: all heads' attn-out visible

  // ---------------- proj (cross-head) + residual ----------------
  f32x4 pj[4][2];
#pragma unroll
  for (int nt = 0; nt < 2; ++nt) {
    const float bp = proj_b[wv * 32 + nt * 16 + l15];
#pragma unroll
    for (int m = 0; m < 4; ++m) pj[m][nt] = (f32x4){bp, bp, bp, bp};
  }
#pragma unroll
  for (int hh = 0; hh < 6; ++hh) {
    const unsigned short* aoh = sm + 64 * XSTR + hh * HREG;
    s16x8 aa[4];
#pragma unroll
    for (int m = 0; m < 4; ++m)
      aa[m] = *(const s16x8*)&aoh[(m * 16 + l15) * 32 + lg * 8];
#pragma unroll
    for (int nt = 0; nt < 2; ++nt) {
      s16x8 wp = *(const s16x8*)&proj_wb[(size_t)(wv * 32 + nt * 16 + l15) * 192 + hh * 32 + lg * 8];
#pragma unroll
      for (int m = 0; m < 4; ++m) pj[m][nt] = MFMA(aa[m], wp, pj[m][nt]);
    }
  }
  // y = x + proj, written back into xa (per-wave-private columns)
#pragma unroll
  for (int m = 0; m < 4; ++m)
#pragma unroll
    for (int nt = 0; nt < 2; ++nt) {
      const int o = wv * 32 + nt * 16 + l15;
#pragma unroll
      for (int r = 0; r < 4; ++r) {
        const int t = m * 16 + lg * 4 + r;
        const float yv = pj[m][nt][r] + b2f(xa[t * XSTR + o]);
        xa[t * XSTR + o] = f2b(yv);
      }
    }
  __syncthreads();  // B6
  // coalesced copy xa[64][192] -> y_win (contiguous 24.6 KB per window)
  unsigned short* ywp = y_win + (size_t)win * 12288;
#pragma unroll
  for (int it = 0; it < 4; ++it) {
    int job = tid + 384 * it;     // job = t*24 + seg
    int t = job / 24;
    int seg = job - t * 24;
    *(u16x8*)&ywp[(size_t)job * 8] = *(const u16x8*)&xa[t * XSTR + seg * 8];
  }
}

// ---------------------------------------------------------------------------
__global__ __launch_bounds__(256) void mlp_kernel(
    const unsigned short* __restrict__ y_win,
    const unsigned short* __restrict__ w1b, const float* __restrict__ b1,
    const unsigned short* __restrict__ w2b, const float* __restrict__ b2,
    float* __restrict__ out) {
  __shared__ __align__(16) unsigned short sm2[2 * 64 * XSTR];  // y_buf + work_buf
  unsigned short* yb = sm2;
  unsigned short* wk = sm2 + 64 * XSTR;

  const int tid  = threadIdx.x;
  const int lane = tid & 63;
  const int wv   = tid >> 6;      // 0..3
  const int l15  = lane & 15;
  const int lg   = lane >> 4;
  const int win  = blockIdx.x;
  const int bb   = win >> 8;
  const int wh   = (win >> 4) & 15;
  const int wwi  = win & 15;

  const unsigned short* ywp = y_win + (size_t)win * 12288;
  // ---- stage y tile (fully coalesced) ----
#pragma unroll
  for (int it = 0; it < 6; ++it) {
    int job = tid + 256 * it;     // 1536
    int t = job / 24;
    int seg = job - t * 24;
    *(u16x8*)&yb[t * XSTR + seg * 8] = *(const u16x8*)&ywp[(size_t)job * 8];
  }
  __syncthreads();  // B0

  // ---- GEMM1: h[t][o] = y . w1^T, wave handles paired a/b channel tiles ----
  int ncol[6];
  f32x4 hacc[4][6];
#pragma unroll
  for (int i = 0; i < 6; ++i) {
    int ntile = (i < 3) ? (3 * wv + i) : (9 + 3 * wv + i);  // a-half / b-half pairs
    ncol[i] = ntile * 16 + l15;
    const float bb1 = b1[ncol[i]];
#pragma unroll
    for (int m = 0; m < 4; ++m) hacc[m][i] = (f32x4){bb1, bb1, bb1, bb1};
  }
#pragma unroll
  for (int ks = 0; ks < 6; ++ks) {
    const int k0 = ks * 32 + lg * 8;
    s16x8 af[4];
#pragma unroll
    for (int m = 0; m < 4; ++m)
      af[m] = *(const s16x8*)&yb[(m * 16 + l15) * XSTR + k0];
#pragma unroll
    for (int i = 0; i < 6; ++i) {
      s16x8 wf = *(const s16x8*)&w1b[(size_t)ncol[i] * 192 + k0];
#pragma unroll
      for (int m = 0; m < 4; ++m) hacc[m][i] = MFMA(af[m], wf, hacc[m][i]);
    }
  }
  // ---- GLU: g = a * sigmoid(b), in-register pairing (i, i+3) ----
#pragma unroll
  for (int m = 0; m < 4; ++m)
#pragma unroll
    for (int i = 0; i < 3; ++i) {
#pragma unroll
      for (int r = 0; r < 4; ++r) {
        const float a = hacc[m][i][r];
        const float bg = hacc[m][i + 3][r];
        const float g = a * (1.0f / (1.0f + __expf(-bg)));
        wk[(m * 16 + lg * 4 + r) * XSTR + ncol[i]] = f2b(g);
      }
    }
  __syncthreads();  // B1: g visible

  // ---- GEMM2: m[t][o] = g . w2^T ----
  int ocol[3];
  f32x4 macc[4][3];
#pragma unroll
  for (int i = 0; i < 3; ++i) {
    ocol[i] = (3 * wv + i) * 16 + l15;
    const float bb2 = b2[ocol[i]];
#pragma unroll
    for (int m = 0; m < 4; ++m) macc[m][i] = (f32x4){bb2, bb2, bb2, bb2};
  }
#pragma unroll
  for (int ks = 0; ks < 6; ++ks) {
    const int k0 = ks * 32 + lg * 8;
    s16x8 gf[4];
#pragma unroll
    for (int m = 0; m < 4; ++m)
      gf[m] = *(const s16x8*)&wk[(m * 16 + l15) * XSTR + k0];
#pragma unroll
    for (int i = 0; i < 3; ++i) {
      s16x8 wf = *(const s16x8*)&w2b[(size_t)ocol[i] * 192 + k0];
#pragma unroll
      for (int m = 0; m < 4; ++m) macc[m][i] = MFMA(gf[m], wf, macc[m][i]);
    }
  }
  __syncthreads();  // B2: all g reads done; m may overwrite wk
#pragma unroll
  for (int m = 0; m < 4; ++m)
#pragma unroll
    for (int i = 0; i < 3; ++i)
#pragma unroll
      for (int r = 0; r < 4; ++r)
        wk[(m * 16 + lg * 4 + r) * XSTR + ocol[i]] = f2b(macc[m][i][r]);
  __syncthreads();  // B3: m visible

  // ---- epilogue: out = y + m, BCHW fp32, 32-B runs ----
  float* obase = out + (size_t)bb * 192 * 16384 + (size_t)(wh * 8) * 128 + wwi * 8;
#pragma unroll
  for (int it = 0; it < 6; ++it) {
    int job = tid + 256 * it;     // job = c + 192*i (c fast -> conflict-free LDS)
    int i = job / 192;
    int c = job - i * 192;
    float vals[8];
#pragma unroll
    for (int j = 0; j < 8; ++j) {
      const int t = i * 8 + j;
      vals[j] = b2f(yb[t * XSTR + c]) + b2f(wk[t * XSTR + c]);
    }
    float* dst = obase + (size_t)c * 16384 + i * 128;
    f32x4 o0 = {vals[0], vals[1], vals[2], vals[3]};
    f32x4 o1 = {vals[4], vals[5], vals[6], vals[7]};
    *(f32x4*)dst = o0;
    *(f32x4*)(dst + 4) = o1;
  }
}

// ---------------------------------------------------------------------------
extern "C" void kernel_launch(void* const* d_in, const int* in_sizes, int n_in,
                              void* d_out, int out_size, void* d_ws, size_t ws_size,
                              hipStream_t stream) {
  (void)in_sizes; (void)n_in; (void)out_size; (void)ws_size;
  const float* x          = (const float*)d_in[0];
  const float* qkv_w      = (const float*)d_in[1];
  const float* qkv_b      = (const float*)d_in[2];
  const float* proj_w     = (const float*)d_in[3];
  const float* proj_b     = (const float*)d_in[4];
  const float* mlp1_w     = (const float*)d_in[5];
  const float* mlp1_b     = (const float*)d_in[6];
  const float* mlp2_w     = (const float*)d_in[7];
  const float* mlp2_b     = (const float*)d_in[8];
  const float* bias_table = (const float*)d_in[9];
  const int*   rel_index  = (const int*)d_in[10];
  float* out = (float*)d_out;

  char* ws = (char*)d_ws;
  unsigned short* qkv_wb  = (unsigned short*)ws + WOFF_QKV;
  unsigned short* proj_wb = (unsigned short*)ws + WOFF_PROJ;
  unsigned short* mlp1_wb = (unsigned short*)ws + WOFF_MLP1;
  unsigned short* mlp2_wb = (unsigned short*)ws + WOFF_MLP2;
  float*          biasx   = (float*)(ws + WOFF_BIASX_BYTES);
  unsigned short* y_win   = (unsigned short*)(ws + WOFF_YWIN_BYTES);

  hipLaunchKernelGGL(prep_kernel, dim3(1024), dim3(256), 0, stream,
                     qkv_w, proj_w, mlp1_w, mlp2_w, bias_table, rel_index,
                     qkv_wb, proj_wb, mlp1_wb, mlp2_wb, biasx);
  hipLaunchKernelGGL(attn_kernel, dim3(2048), dim3(384), 0, stream,
                     x, qkv_wb, qkv_b, proj_wb, proj_b, biasx, y_win);
  hipLaunchKernelGGL(mlp_kernel, dim3(2048), dim3(256), 0, stream,
                     y_win, mlp1_wb, mlp1_b, mlp2_wb, mlp2_b, out);
}

// Round 4
// 282.266 us; speedup vs baseline: 1.0922x; 1.0922x over previous
//
#include <hip/hip_runtime.h>

// ---------------------------------------------------------------------------
// Swin-style windowed MHA block, MI355X/gfx950.
// R4: attn LDS 114.7KB -> 72KB (register residual + XOR-swizzled unpadded
// head buffers overlaying xa) => 2 blocks/CU; XCD-aware window swizzle.
// ---------------------------------------------------------------------------

typedef short          s16x8 __attribute__((ext_vector_type(8)));
typedef unsigned short u16x4 __attribute__((ext_vector_type(4)));
typedef unsigned short u16x8 __attribute__((ext_vector_type(8)));
typedef float          f32x4 __attribute__((ext_vector_type(4)));

#define MFMA(A, B, C) __builtin_amdgcn_mfma_f32_16x16x32_bf16((A), (B), (C), 0, 0, 0)

__device__ __forceinline__ unsigned short f2b(float f) {
  unsigned x = __float_as_uint(f);
  x = (x + 0x7FFFu + ((x >> 16) & 1u)) >> 16;   // RNE
  return (unsigned short)x;
}
__device__ __forceinline__ float b2f(unsigned short u) {
  return __uint_as_float(((unsigned)u) << 16);
}

// XOR-chunk swizzles (8-elem = 16B chunks stay contiguous -> b128-aligned)
__device__ __forceinline__ int swzQ(int t, int ch) {   // [64][32] tiles
  return t * 32 + ((((ch >> 3) ^ t) & 3) << 3) + (ch & 7);
}
__device__ __forceinline__ int swzP(int q, int k) {    // [64][64] tiles
  return q * 64 + ((((k >> 3) ^ q) & 7) << 3) + (k & 7);
}

#define XSTR   200      // padded row stride (elems) for [64][192] LDS tiles
#define HSZ    6144     // per-head LDS elems: Q(2048)+K(2048)+Vt(2048); P,AO overlay
#define QSCALE 0.17677669529663687f

// workspace element offsets (ushort units unless noted)
#define WOFF_QKV   0
#define WOFF_PROJ  110592
#define WOFF_MLP1  147456
#define WOFF_MLP2  221184
#define WOFF_BIASX_BYTES 516096           // float[4096]
#define WOFF_YWIN_BYTES  532480           // ushort[2048*64*192]

// ---------------------------------------------------------------------------
__global__ void prep_kernel(const float* __restrict__ qkv_w,
                            const float* __restrict__ proj_w,
                            const float* __restrict__ mlp1_w,
                            const float* __restrict__ mlp2_w,
                            const float* __restrict__ bias_table,
                            const int*   __restrict__ rel_index,
                            unsigned short* __restrict__ qkv_wb,
                            unsigned short* __restrict__ proj_wb,
                            unsigned short* __restrict__ mlp1_wb,
                            unsigned short* __restrict__ mlp2_wb,
                            float* __restrict__ biasx) {
  int j = blockIdx.x * 256 + threadIdx.x;   // 1024*256 = 262144 jobs exactly
  if (j < 110592) {
    float v = qkv_w[j];
    if (j < 36864) v *= QSCALE;             // fold 1/sqrt(HD) into Q rows
    qkv_wb[j] = f2b(v);
  } else if (j < 147456) {
    proj_wb[j - 110592] = f2b(proj_w[j - 110592]);
  } else if (j < 221184) {
    mlp1_wb[j - 147456] = f2b(mlp1_w[j - 147456]);
  } else if (j < 258048) {
    mlp2_wb[j - 221184] = f2b(mlp2_w[j - 221184]);
  } else {
    int e = j - 258048;                     // 0..4095
    int l = e >> 6, v = e & 63;
    int tm = v >> 4, tn = (v >> 2) & 3, r = v & 3;
    int q = tn * 16 + (l & 15);
    int k = tm * 16 + (l >> 4) * 4 + r;
    biasx[e] = bias_table[rel_index[q * 64 + k]];
  }
}

// ---------------------------------------------------------------------------
__global__ __launch_bounds__(384, 3) void attn_kernel(
    const float* __restrict__ x,
    const unsigned short* __restrict__ qkv_wb, const float* __restrict__ qkv_b,
    const unsigned short* __restrict__ proj_wb, const float* __restrict__ proj_b,
    const float* __restrict__ biasx,
    unsigned short* __restrict__ y_win) {
  __shared__ __align__(16) unsigned short sm[6 * HSZ];  // 73728 B -> 2 blocks/CU

  const int tid  = threadIdx.x;
  const int lane = tid & 63;
  const int wv   = tid >> 6;      // head index, 0..5
  const int l15  = lane & 15;
  const int lg   = lane >> 4;     // 0..3
  // XCD-aware bijective swizzle: 2048 = 8 XCDs * 256 -> contiguous win range/XCD
  const int win  = ((blockIdx.x & 7) << 8) | (blockIdx.x >> 3);
  const int bb   = win >> 8;
  const int wh   = (win >> 4) & 15;
  const int wwi  = win & 15;

  unsigned short* xa = sm;        // [64 tokens][XSTR] bf16 of x-window (dies at B1)
  const float* xwin = x + (size_t)bb * 192 * 16384 + (size_t)(wh * 8) * 128 + wwi * 8;

  // ---- stage x window -> LDS bf16 (jobs: 192 ch * 8 rows, 32B reads) ----
#pragma unroll
  for (int it = 0; it < 4; ++it) {
    int job = tid + 384 * it;     // 1536 jobs
    int c = job >> 3, i = job & 7;
    const float* src = xwin + (size_t)c * 16384 + i * 128;
    f32x4 v0 = *(const f32x4*)(src);
    f32x4 v1 = *(const f32x4*)(src + 4);
    unsigned short* dst = &xa[(i * 8) * XSTR + c];
    dst[0 * XSTR] = f2b(v0[0]); dst[1 * XSTR] = f2b(v0[1]);
    dst[2 * XSTR] = f2b(v0[2]); dst[3 * XSTR] = f2b(v0[3]);
    dst[4 * XSTR] = f2b(v1[0]); dst[5 * XSTR] = f2b(v1[1]);
    dst[6 * XSTR] = f2b(v1[2]); dst[7 * XSTR] = f2b(v1[3]);
  }
  __syncthreads();  // B0: xa visible to all waves

  unsigned short* hreg = sm + wv * HSZ;   // per-head region (wave-private B1..B2)
  unsigned short* Qs  = hreg;             // [64][32] swzQ
  unsigned short* Ks  = hreg + 2048;      // [64][32] swzQ
  unsigned short* Vts = hreg + 4096;      // [32][64] swzP (V transposed)
  unsigned short* Ps  = hreg;             // [64][64] swzP, overlays Q+K
  unsigned short* AO  = hreg + 4096;      // [64][32] swzQ, overlays Vt

  // ---------------- QKV GEMM: [64x192] x [192x32] per head, x3 ----------------
  f32x4 accq[4][2], acck[4][2], accv[4][2];
#pragma unroll
  for (int nt = 0; nt < 2; ++nt) {
    const int o = wv * 32 + nt * 16 + l15;
    const float bq = qkv_b[o] * QSCALE;
    const float bk = qkv_b[192 + o];
    const float bv = qkv_b[384 + o];
#pragma unroll
    for (int m = 0; m < 4; ++m) {
      accq[m][nt] = (f32x4){bq, bq, bq, bq};
      acck[m][nt] = (f32x4){bk, bk, bk, bk};
      accv[m][nt] = (f32x4){bv, bv, bv, bv};
    }
  }
#pragma unroll
  for (int ks = 0; ks < 6; ++ks) {
    const int k0 = ks * 32 + lg * 8;
    s16x8 af[4];
#pragma unroll
    for (int m = 0; m < 4; ++m)
      af[m] = *(const s16x8*)&xa[(m * 16 + l15) * XSTR + k0];
#pragma unroll
    for (int nt = 0; nt < 2; ++nt) {
      const int o = wv * 32 + nt * 16 + l15;
      s16x8 wq  = *(const s16x8*)&qkv_wb[(size_t)o * 192 + k0];
      s16x8 wk  = *(const s16x8*)&qkv_wb[(size_t)(192 + o) * 192 + k0];
      s16x8 wvv = *(const s16x8*)&qkv_wb[(size_t)(384 + o) * 192 + k0];
#pragma unroll
      for (int m = 0; m < 4; ++m) {
        accq[m][nt] = MFMA(af[m], wq , accq[m][nt]);
        acck[m][nt] = MFMA(af[m], wk , acck[m][nt]);
        accv[m][nt] = MFMA(af[m], wvv, accv[m][nt]);
      }
    }
  }
  // ---- residual slice -> registers (frees xa region for Q/K/Vt) ----
  u16x4 resv[4][2];
#pragma unroll
  for (int m = 0; m < 4; ++m)
#pragma unroll
    for (int nt = 0; nt < 2; ++nt)
#pragma unroll
      for (int r = 0; r < 4; ++r)
        resv[m][nt][r] = xa[(m * 16 + lg * 4 + r) * XSTR + wv * 32 + nt * 16 + l15];
  __syncthreads();  // B1: all xa reads complete -> head buffers may overwrite

  // write Q,K (swzQ scalar); Vt transposed (swzP, packed b64)
#pragma unroll
  for (int m = 0; m < 4; ++m) {
#pragma unroll
    for (int nt = 0; nt < 2; ++nt) {
      const int d = nt * 16 + l15;
#pragma unroll
      for (int r = 0; r < 4; ++r) {
        const int t = m * 16 + lg * 4 + r;
        Qs[swzQ(t, d)] = f2b(accq[m][nt][r]);
        Ks[swzQ(t, d)] = f2b(acck[m][nt][r]);
      }
      u16x4 pv;
      pv[0] = f2b(accv[m][nt][0]); pv[1] = f2b(accv[m][nt][1]);
      pv[2] = f2b(accv[m][nt][2]); pv[3] = f2b(accv[m][nt][3]);
      *(u16x4*)&Vts[swzP(d, m * 16 + lg * 4)] = pv;
    }
  }
  // (no barrier: head region is wave-private; in-wave LDS order via data deps)

  // ---------------- scores^T = K . Q^T + bias ----------------
  const float* bxp = biasx + lane * 64;
  s16x8 kf[4], qf[4];
#pragma unroll
  for (int tm = 0; tm < 4; ++tm)
    kf[tm] = *(const s16x8*)&Ks[swzQ(tm * 16 + l15, lg * 8)];
#pragma unroll
  for (int tn = 0; tn < 4; ++tn)
    qf[tn] = *(const s16x8*)&Qs[swzQ(tn * 16 + l15, lg * 8)];
  f32x4 sc[4][4];
#pragma unroll
  for (int tm = 0; tm < 4; ++tm)
#pragma unroll
    for (int tn = 0; tn < 4; ++tn) {
      f32x4 bfr = *(const f32x4*)&bxp[tm * 16 + tn * 4];
      sc[tm][tn] = MFMA(kf[tm], qf[tn], bfr);
    }
  // softmax over keys (rows of scores^T): 16 in-lane + shfl_xor 16,32
#pragma unroll
  for (int tn = 0; tn < 4; ++tn) {
    float mx = sc[0][tn][0];
#pragma unroll
    for (int tm = 0; tm < 4; ++tm)
#pragma unroll
      for (int r = 0; r < 4; ++r) mx = fmaxf(mx, sc[tm][tn][r]);
    mx = fmaxf(mx, __shfl_xor(mx, 16));
    mx = fmaxf(mx, __shfl_xor(mx, 32));
    float sum = 0.f;
#pragma unroll
    for (int tm = 0; tm < 4; ++tm)
#pragma unroll
      for (int r = 0; r < 4; ++r) {
        float e = __expf(sc[tm][tn][r] - mx);
        sc[tm][tn][r] = e;
        sum += e;
      }
    sum += __shfl_xor(sum, 16);
    sum += __shfl_xor(sum, 32);
    const float inv = 1.0f / sum;
#pragma unroll
    for (int tm = 0; tm < 4; ++tm)
#pragma unroll
      for (int r = 0; r < 4; ++r) sc[tm][tn][r] *= inv;
  }
  // write P over Q/K (kf/qf already consumed; wave-private; data-dep ordered)
#pragma unroll
  for (int tm = 0; tm < 4; ++tm)
#pragma unroll
    for (int tn = 0; tn < 4; ++tn) {
      u16x4 pv;
      pv[0] = f2b(sc[tm][tn][0]); pv[1] = f2b(sc[tm][tn][1]);
      pv[2] = f2b(sc[tm][tn][2]); pv[3] = f2b(sc[tm][tn][3]);
      *(u16x4*)&Ps[swzP(tn * 16 + l15, tm * 16 + lg * 4)] = pv;
    }

  // ---------------- PV: out[q][d] = P[64x64] . V[64x32] ----------------
  f32x4 oacc[4][2];
#pragma unroll
  for (int m = 0; m < 4; ++m)
#pragma unroll
    for (int nt = 0; nt < 2; ++nt) oacc[m][nt] = (f32x4){0.f, 0.f, 0.f, 0.f};
#pragma unroll
  for (int ks = 0; ks < 2; ++ks) {
    s16x8 ap[4], bv2[2];
#pragma unroll
    for (int m = 0; m < 4; ++m)
      ap[m] = *(const s16x8*)&Ps[swzP(m * 16 + l15, ks * 32 + lg * 8)];
#pragma unroll
    for (int nt = 0; nt < 2; ++nt)
      bv2[nt] = *(const s16x8*)&Vts[swzP(nt * 16 + l15, ks * 32 + lg * 8)];
#pragma unroll
    for (int m = 0; m < 4; ++m)
#pragma unroll
      for (int nt = 0; nt < 2; ++nt)
        oacc[m][nt] = MFMA(ap[m], bv2[nt], oacc[m][nt]);
  }
  // write attn-out over Vt (bv2 consumed; wave-private; data-dep ordered)
#pragma unroll
  for (int m = 0; m < 4; ++m)
#pragma unroll
    for (int nt = 0; nt < 2; ++nt) {
      const int d = nt * 16 + l15;
#pragma unroll
      for (int r = 0; r < 4; ++r)
        AO[swzQ(m * 16 + lg * 4 + r, d)] = f2b(oacc[m][nt][r]);
    }
  __syncthreads();  // B2: all heads' attn-out visible

  // ---------------- proj (cross-head) + residual ----------------
  f32x4 pj[4][2];
#pragma unroll
  for (int nt = 0; nt < 2; ++nt) {
    const float bp = proj_b[wv * 32 + nt * 16 + l15];
#pragma unroll
    for (int m = 0; m < 4; ++m) pj[m][nt] = (f32x4){bp, bp, bp, bp};
  }
#pragma unroll
  for (int hh = 0; hh < 6; ++hh) {
    const unsigned short* aoh = sm + hh * HSZ + 4096;
    s16x8 aa[4];
#pragma unroll
    for (int m = 0; m < 4; ++m)
      aa[m] = *(const s16x8*)&aoh[swzQ(m * 16 + l15, lg * 8)];
#pragma unroll
    for (int nt = 0; nt < 2; ++nt) {
      s16x8 wp = *(const s16x8*)&proj_wb[(size_t)(wv * 32 + nt * 16 + l15) * 192 + hh * 32 + lg * 8];
#pragma unroll
      for (int m = 0; m < 4; ++m) pj[m][nt] = MFMA(aa[m], wp, pj[m][nt]);
    }
  }
  __syncthreads();  // B3: all proj reads done -> sm reusable as ybuf

  // y = x + proj scattered into ybuf (first 12800 elems of sm)
  unsigned short* ybuf = sm;
#pragma unroll
  for (int m = 0; m < 4; ++m)
#pragma unroll
    for (int nt = 0; nt < 2; ++nt) {
      const int o = wv * 32 + nt * 16 + l15;
#pragma unroll
      for (int r = 0; r < 4; ++r) {
        const int t = m * 16 + lg * 4 + r;
        ybuf[t * XSTR + o] = f2b(pj[m][nt][r] + b2f(resv[m][nt][r]));
      }
    }
  __syncthreads();  // B4
  // coalesced copy ybuf[64][192] -> y_win (contiguous 24.6 KB per window)
  unsigned short* ywp = y_win + (size_t)win * 12288;
#pragma unroll
  for (int it = 0; it < 4; ++it) {
    int job = tid + 384 * it;     // job = t*24 + seg
    int t = job / 24;
    int seg = job - t * 24;
    *(u16x8*)&ywp[(size_t)job * 8] = *(const u16x8*)&ybuf[t * XSTR + seg * 8];
  }
}

// ---------------------------------------------------------------------------
__global__ __launch_bounds__(256) void mlp_kernel(
    const unsigned short* __restrict__ y_win,
    const unsigned short* __restrict__ w1b, const float* __restrict__ b1,
    const unsigned short* __restrict__ w2b, const float* __restrict__ b2,
    float* __restrict__ out) {
  __shared__ __align__(16) unsigned short sm2[2 * 64 * XSTR];  // y_buf + work_buf
  unsigned short* yb = sm2;
  unsigned short* wk = sm2 + 64 * XSTR;

  const int tid  = threadIdx.x;
  const int lane = tid & 63;
  const int wv   = tid >> 6;      // 0..3
  const int l15  = lane & 15;
  const int lg   = lane >> 4;
  const int win  = ((blockIdx.x & 7) << 8) | (blockIdx.x >> 3);
  const int bb   = win >> 8;
  const int wh   = (win >> 4) & 15;
  const int wwi  = win & 15;

  const unsigned short* ywp = y_win + (size_t)win * 12288;
  // ---- stage y tile (fully coalesced) ----
#pragma unroll
  for (int it = 0; it < 6; ++it) {
    int job = tid + 256 * it;     // 1536
    int t = job / 24;
    int seg = job - t * 24;
    *(u16x8*)&yb[t * XSTR + seg * 8] = *(const u16x8*)&ywp[(size_t)job * 8];
  }
  __syncthreads();  // B0

  // ---- GEMM1: h[t][o] = y . w1^T, wave handles paired a/b channel tiles ----
  int ncol[6];
  f32x4 hacc[4][6];
#pragma unroll
  for (int i = 0; i < 6; ++i) {
    int ntile = (i < 3) ? (3 * wv + i) : (9 + 3 * wv + i);  // a-half / b-half pairs
    ncol[i] = ntile * 16 + l15;
    const float bb1 = b1[ncol[i]];
#pragma unroll
    for (int m = 0; m < 4; ++m) hacc[m][i] = (f32x4){bb1, bb1, bb1, bb1};
  }
#pragma unroll
  for (int ks = 0; ks < 6; ++ks) {
    const int k0 = ks * 32 + lg * 8;
    s16x8 af[4];
#pragma unroll
    for (int m = 0; m < 4; ++m)
      af[m] = *(const s16x8*)&yb[(m * 16 + l15) * XSTR + k0];
#pragma unroll
    for (int i = 0; i < 6; ++i) {
      s16x8 wf = *(const s16x8*)&w1b[(size_t)ncol[i] * 192 + k0];
#pragma unroll
      for (int m = 0; m < 4; ++m) hacc[m][i] = MFMA(af[m], wf, hacc[m][i]);
    }
  }
  // ---- GLU: g = a * sigmoid(b), in-register pairing (i, i+3) ----
#pragma unroll
  for (int m = 0; m < 4; ++m)
#pragma unroll
    for (int i = 0; i < 3; ++i) {
#pragma unroll
      for (int r = 0; r < 4; ++r) {
        const float a = hacc[m][i][r];
        const float bg = hacc[m][i + 3][r];
        const float g = a * (1.0f / (1.0f + __expf(-bg)));
        wk[(m * 16 + lg * 4 + r) * XSTR + ncol[i]] = f2b(g);
      }
    }
  __syncthreads();  // B1: g visible

  // ---- GEMM2: m[t][o] = g . w2^T ----
  int ocol[3];
  f32x4 macc[4][3];
#pragma unroll
  for (int i = 0; i < 3; ++i) {
    ocol[i] = (3 * wv + i) * 16 + l15;
    const float bb2 = b2[ocol[i]];
#pragma unroll
    for (int m = 0; m < 4; ++m) macc[m][i] = (f32x4){bb2, bb2, bb2, bb2};
  }
#pragma unroll
  for (int ks = 0; ks < 6; ++ks) {
    const int k0 = ks * 32 + lg * 8;
    s16x8 gf[4];
#pragma unroll
    for (int m = 0; m < 4; ++m)
      gf[m] = *(const s16x8*)&wk[(m * 16 + l15) * XSTR + k0];
#pragma unroll
    for (int i = 0; i < 3; ++i) {
      s16x8 wf = *(const s16x8*)&w2b[(size_t)ocol[i] * 192 + k0];
#pragma unroll
      for (int m = 0; m < 4; ++m) macc[m][i] = MFMA(gf[m], wf, macc[m][i]);
    }
  }
  __syncthreads();  // B2: all g reads done; m may overwrite wk
#pragma unroll
  for (int m = 0; m < 4; ++m)
#pragma unroll
    for (int i = 0; i < 3; ++i)
#pragma unroll
      for (int r = 0; r < 4; ++r)
        wk[(m * 16 + lg * 4 + r) * XSTR + ocol[i]] = f2b(macc[m][i][r]);
  __syncthreads();  // B3: m visible

  // ---- epilogue: out = y + m, BCHW fp32, 32-B runs ----
  float* obase = out + (size_t)bb * 192 * 16384 + (size_t)(wh * 8) * 128 + wwi * 8;
#pragma unroll
  for (int it = 0; it < 6; ++it) {
    int job = tid + 256 * it;     // job = c + 192*i (c fast -> conflict-free LDS)
    int i = job / 192;
    int c = job - i * 192;
    float vals[8];
#pragma unroll
    for (int j = 0; j < 8; ++j) {
      const int t = i * 8 + j;
      vals[j] = b2f(yb[t * XSTR + c]) + b2f(wk[t * XSTR + c]);
    }
    float* dst = obase + (size_t)c * 16384 + i * 128;
    f32x4 o0 = {vals[0], vals[1], vals[2], vals[3]};
    f32x4 o1 = {vals[4], vals[5], vals[6], vals[7]};
    *(f32x4*)dst = o0;
    *(f32x4*)(dst + 4) = o1;
  }
}

// ---------------------------------------------------------------------------
extern "C" void kernel_launch(void* const* d_in, const int* in_sizes, int n_in,
                              void* d_out, int out_size, void* d_ws, size_t ws_size,
                              hipStream_t stream) {
  (void)in_sizes; (void)n_in; (void)out_size; (void)ws_size;
  const float* x          = (const float*)d_in[0];
  const float* qkv_w      = (const float*)d_in[1];
  const float* qkv_b      = (const float*)d_in[2];
  const float* proj_w     = (const float*)d_in[3];
  const float* proj_b     = (const float*)d_in[4];
  const float* mlp1_w     = (const float*)d_in[5];
  const float* mlp1_b     = (const float*)d_in[6];
  const float* mlp2_w     = (const float*)d_in[7];
  const float* mlp2_b     = (const float*)d_in[8];
  const float* bias_table = (const float*)d_in[9];
  const int*   rel_index  = (const int*)d_in[10];
  float* out = (float*)d_out;

  char* ws = (char*)d_ws;
  unsigned short* qkv_wb  = (unsigned short*)ws + WOFF_QKV;
  unsigned short* proj_wb = (unsigned short*)ws + WOFF_PROJ;
  unsigned short* mlp1_wb = (unsigned short*)ws + WOFF_MLP1;
  unsigned short* mlp2_wb = (unsigned short*)ws + WOFF_MLP2;
  float*          biasx   = (float*)(ws + WOFF_BIASX_BYTES);
  unsigned short* y_win   = (unsigned short*)(ws + WOFF_YWIN_BYTES);

  hipLaunchKernelGGL(prep_kernel, dim3(1024), dim3(256), 0, stream,
                     qkv_w, proj_w, mlp1_w, mlp2_w, bias_table, rel_index,
                     qkv_wb, proj_wb, mlp1_wb, mlp2_wb, biasx);
  hipLaunchKernelGGL(attn_kernel, dim3(2048), dim3(384), 0, stream,
                     x, qkv_wb, qkv_b, proj_wb, proj_b, biasx, y_win);
  hipLaunchKernelGGL(mlp_kernel, dim3(2048), dim3(256), 0, stream,
                     y_win, mlp1_wb, mlp1_b, mlp2_wb, mlp2_b, out);
}